// Round 2
// baseline (633.119 us; speedup 1.0000x reference)
//
#include <hip/hip_runtime.h>
#include <hip/hip_bf16.h>

#define N_NODES 100000
#define N_EDGES 1600000
#define IN_C 128
#define HID_C 256
#define OUT_C 128

typedef __attribute__((ext_vector_type(8))) short bf16x8;
typedef __attribute__((ext_vector_type(4))) float f32x4;
typedef __attribute__((ext_vector_type(2))) float f32x2;

static __device__ __forceinline__ short f2bf(float f) {
    union { float f; unsigned u; } x{f};
    unsigned r = (x.u + 0x7fffu + ((x.u >> 16) & 1u)) >> 16;
    return (short)r;
}
static __device__ __forceinline__ f32x2 bfpair(unsigned d) {
    union { unsigned u; float f; } lo, hi;
    lo.u = d << 16;
    hi.u = d & 0xffff0000u;
    return f32x2{lo.f, hi.f};
}

// ================= CSR build =================
__global__ void hist_rank(const int* __restrict__ rows, int* __restrict__ deg,
                          int* __restrict__ rank, int E)
{
    int e = blockIdx.x * blockDim.x + threadIdx.x;
    if (e < E) rank[e] = atomicAdd(&deg[rows[e]], 1);
}

#define SCAN_BLOCK 256
#define SCAN_ELEMS 1024

__global__ __launch_bounds__(SCAN_BLOCK) void scan1(const int* __restrict__ deg,
                                                    int* __restrict__ excl,
                                                    int* __restrict__ bsum, int N)
{
    __shared__ int sh[SCAN_BLOCK];
    int t = threadIdx.x;
    int base = blockIdx.x * SCAN_ELEMS + t * 4;
    int v[4];
    #pragma unroll
    for (int i = 0; i < 4; ++i) {
        int idx = base + i;
        v[i] = (idx < N) ? deg[idx] : 0;
    }
    int s = v[0] + v[1] + v[2] + v[3];
    sh[t] = s;
    __syncthreads();
    for (int d = 1; d < SCAN_BLOCK; d <<= 1) {
        int add = (t >= d) ? sh[t - d] : 0;
        __syncthreads();
        sh[t] += add;
        __syncthreads();
    }
    int p = sh[t] - s;
    #pragma unroll
    for (int i = 0; i < 4; ++i) {
        int idx = base + i;
        if (idx < N) excl[idx] = p;
        p += v[i];
    }
    if (t == SCAN_BLOCK - 1) bsum[blockIdx.x] = sh[t];
}

// scan2 folded in: every block recomputes the (<=128-entry) block-sum prefix in LDS.
__global__ void scan3(int* __restrict__ row_start, const int* __restrict__ bsum,
                      int NB, int N, int E)
{
    __shared__ int pref[128];
    int t = threadIdx.x;
    if (t < 128) pref[t] = (t < NB) ? bsum[t] : 0;
    __syncthreads();
    for (int d = 1; d < 128; d <<= 1) {
        int add = (t < 128 && t >= d) ? pref[t - d] : 0;
        __syncthreads();
        if (t < 128) pref[t] += add;
        __syncthreads();
    }
    int i = blockIdx.x * blockDim.x + t;
    if (i < N) {
        int b = i >> 10;
        row_start[i] += (b == 0) ? 0 : pref[b - 1];
    } else if (i == N) {
        row_start[N] = E;
    }
}

// atomic-free scatter fused with bf16 casts (wave-aligned seam: E % 64 == 0)
__global__ void scatter_cast(const int* __restrict__ rows, const int* __restrict__ cols,
                             const float* __restrict__ vals, const int* __restrict__ row_start,
                             const int* __restrict__ rank, int2* __restrict__ epk, int E,
                             const float* __restrict__ s0, short* __restrict__ d0, int n0,
                             const float* __restrict__ s1, short* __restrict__ d1, int n1,
                             const float* __restrict__ s2, short* __restrict__ d2, int n2,
                             const float* __restrict__ s3, short* __restrict__ d3, int n3)
{
    int idx = blockIdx.x * blockDim.x + threadIdx.x;
    if (idx < E) {
        int pos = row_start[rows[idx]] + rank[idx];
        epk[pos] = int2{cols[idx], __float_as_int(vals[idx])};
    } else {
        int i = (idx - E) * 4;
        int castN = n0 + n1 + n2 + n3;
        if (i >= castN) return;
        const float* s; short* d;
        if (i < n0) { s = s0; d = d0; }
        else if ((i -= n0) < n1) { s = s1; d = d1; }
        else if ((i -= n1) < n2) { s = s2; d = d2; }
        else { i -= n2; s = s3; d = d3; }
        float4 v = *(const float4*)(s + i);
        *(short4*)(d + i) = short4{f2bf(v.x), f2bf(v.y), f2bf(v.z), f2bf(v.w)};
    }
}

// ================= gather SpMM, batched (8 edges in flight) =================
template<int B, int ND>
static __device__ __forceinline__ void spmm_batch(
    const unsigned* __restrict__ Hb, const int2* __restrict__ epk,
    int j, int loff, f32x2* acc)
{
    int2 e[B];
    #pragma unroll
    for (int b = 0; b < B; ++b) e[b] = epk[j + b];
    uint2 g[B];
    #pragma unroll
    for (int b = 0; b < B; ++b) {
        const unsigned* p = Hb + (size_t)e[b].x * (64 * ND) + loff;
        if constexpr (ND == 2) g[b] = *(const uint2*)p;
        else                   g[b].x = *p;
    }
    #pragma unroll
    for (int b = 0; b < B; ++b) {
        float v = __int_as_float(e[b].y);
        acc[0] += v * bfpair(g[b].x);
        if constexpr (ND == 2) acc[1] += v * bfpair(g[b].y);
    }
}

// MODE 0: write bf16. MODE 2: (C==128) add bias, L2-normalize row, write fp32.
template<int C, int MODE>
__global__ __launch_bounds__(256) void spmm_gather(
    const short* __restrict__ H, const int* __restrict__ row_start,
    const int2* __restrict__ epk, void* __restrict__ outv,
    const float* __restrict__ bias, int N)
{
    constexpr int PL = C / 64;
    constexpr int ND = PL / 2;
    int wid = threadIdx.x >> 6;
    int lane = threadIdx.x & 63;
    int row = blockIdx.x * 4 + wid;
    if (row >= N) return;
    int j = row_start[row];
    int end = row_start[row + 1];
    const unsigned* Hb = (const unsigned*)H;
    const int loff = lane * ND;

    f32x2 acc[ND];
    #pragma unroll
    for (int d = 0; d < ND; ++d) acc[d] = f32x2{0.f, 0.f};

    for (; j + 8 <= end; j += 8) spmm_batch<8, ND>(Hb, epk, j, loff, acc);
    if (j + 4 <= end) { spmm_batch<4, ND>(Hb, epk, j, loff, acc); j += 4; }
    if (j + 2 <= end) { spmm_batch<2, ND>(Hb, epk, j, loff, acc); j += 2; }
    if (j < end)      { spmm_batch<1, ND>(Hb, epk, j, loff, acc); }

    if constexpr (MODE == 0) {
        unsigned od[ND];
        #pragma unroll
        for (int d = 0; d < ND; ++d)
            od[d] = (unsigned)(unsigned short)f2bf(acc[d].x)
                  | ((unsigned)(unsigned short)f2bf(acc[d].y) << 16);
        unsigned* orow = (unsigned*)outv + (size_t)row * (64 * ND) + loff;
        if constexpr (ND == 2) *(uint2*)orow = uint2{od[0], od[1]};
        else                   *orow = od[0];
    } else {
        int ch = lane * 2;
        float o0 = acc[0].x + bias[ch];
        float o1 = acc[0].y + bias[ch + 1];
        float ss = o0 * o0 + o1 * o1;
        #pragma unroll
        for (int d = 1; d < 64; d <<= 1)
            ss += __shfl_xor(ss, d);
        float s = 1.0f / fmaxf(sqrtf(ss), 1e-12f);
        *(float2*)((float*)outv + (size_t)row * C + ch) = float2{o0 * s, o1 * s};
    }
}

// ================= fused gather-SpMM + dense GEMM (+optional 2nd GEMM) ==========
// Block = 256 threads (4 waves), owns 64 output rows.
// Phase A: each wave gathers 16 rows (identical inner loop to spmm_gather),
//          rounds to bf16 and stages the [64 x CIN] tile in LDS.
// Phase B: tile @ W^T  ([COUT x CIN] row-major, read as MFMA B-frags straight
//          from global; W is tiny and L2-resident), +bias, relu.
// Phase C (FUSE3): restage relu'd [64 x COUT] tile in LDS, multiply by
//          W3^T ([C3 x COUT]) and write bf16 (no bias/relu -> added downstream).
// Numerics identical to the unfused spmm->gemm chain (same bf16 rounding points).
template<int CIN, int COUT, bool FUSE3, int C3>
__global__ __launch_bounds__(256, 4) void spmm_gemm(
    const short* __restrict__ H, const int* __restrict__ row_start,
    const int2* __restrict__ epk,
    const short* __restrict__ W, const float* __restrict__ bias,
    const short* __restrict__ W3,
    short* __restrict__ Y, short* __restrict__ Y3, int N)
{
    static_assert(!FUSE3 || CIN == COUT, "phase-C restages into the same LDS tile");
    constexpr int ND = CIN / 128;          // unsigneds (bf16 pairs) per lane per row
    constexpr int LDW = CIN + 8;           // LDS row stride in shorts
    __shared__ short As[64][LDW];

    const int tid = threadIdx.x;
    const int wid = tid >> 6;
    const int lane = tid & 63;
    const int rb = blockIdx.x * 64;

    // ---------- phase A: gather 16 rows per wave ----------
    {
        const unsigned* Hb = (const unsigned*)H;
        const int loff = lane * ND;
        for (int rr = 0; rr < 16; ++rr) {
            const int lr = wid * 16 + rr;
            const int row = rb + lr;
            f32x2 acc[ND];
            #pragma unroll
            for (int d = 0; d < ND; ++d) acc[d] = f32x2{0.f, 0.f};
            if (row < N) {
                int j = row_start[row];
                const int end = row_start[row + 1];
                for (; j + 8 <= end; j += 8) spmm_batch<8, ND>(Hb, epk, j, loff, acc);
                if (j + 4 <= end) { spmm_batch<4, ND>(Hb, epk, j, loff, acc); j += 4; }
                if (j + 2 <= end) { spmm_batch<2, ND>(Hb, epk, j, loff, acc); j += 2; }
                if (j < end)      spmm_batch<1, ND>(Hb, epk, j, loff, acc);
            }
            if constexpr (ND == 2) {
                unsigned o0 = (unsigned)(unsigned short)f2bf(acc[0].x)
                            | ((unsigned)(unsigned short)f2bf(acc[0].y) << 16);
                unsigned o1 = (unsigned)(unsigned short)f2bf(acc[1].x)
                            | ((unsigned)(unsigned short)f2bf(acc[1].y) << 16);
                *(uint2*)&As[lr][4 * lane] = uint2{o0, o1};
            } else {
                unsigned o0 = (unsigned)(unsigned short)f2bf(acc[0].x)
                            | ((unsigned)(unsigned short)f2bf(acc[0].y) << 16);
                *(unsigned*)&As[lr][2 * lane] = o0;
            }
        }
    }
    __syncthreads();

    // ---------- phase B: [64 x CIN] @ W[COUT x CIN]^T ----------
    const int wm = wid & 1;        // 32-row half
    const int wn = wid >> 1;       // COUT/2 col half
    const int l15 = lane & 15;
    const int quad = lane >> 4;
    constexpr int NT = COUT / 32;  // 16-wide frags per wave along COUT
    f32x4 acc[2][NT] = {};

    for (int k0 = 0; k0 < CIN; k0 += 32) {
        bf16x8 aF[2];
        #pragma unroll
        for (int mt = 0; mt < 2; ++mt)
            aF[mt] = *(const bf16x8*)&As[wm * 32 + mt * 16 + l15][k0 + quad * 8];
        #pragma unroll
        for (int nc = 0; nc < NT; nc += 4) {      // 4-wide bF chunks cap VGPR pressure
            bf16x8 bF[4];
            #pragma unroll
            for (int i = 0; i < 4; ++i) {
                const int col = wn * (COUT / 2) + (nc + i) * 16 + l15;
                bF[i] = *(const bf16x8*)&W[(size_t)col * CIN + k0 + quad * 8];
            }
            #pragma unroll
            for (int mt = 0; mt < 2; ++mt)
                #pragma unroll
                for (int i = 0; i < 4; ++i)
                    acc[mt][nc + i] = __builtin_amdgcn_mfma_f32_16x16x32_bf16(
                        aF[mt], bF[i], acc[mt][nc + i], 0, 0, 0);
        }
    }

    if constexpr (!FUSE3) {
        // epilogue: bias + relu, store bf16
        #pragma unroll
        for (int nt = 0; nt < NT; ++nt) {
            const int col = wn * (COUT / 2) + nt * 16 + l15;
            const float bv = bias[col];
            #pragma unroll
            for (int mt = 0; mt < 2; ++mt) {
                const int row0 = rb + wm * 32 + mt * 16 + quad * 4;
                #pragma unroll
                for (int r = 0; r < 4; ++r) {
                    const int row = row0 + r;
                    if (row < N)
                        Y[(size_t)row * COUT + col] = f2bf(fmaxf(acc[mt][nt][r] + bv, 0.f));
                }
            }
        }
    } else {
        __syncthreads();   // all waves done reading As (phase-B K-loop)
        // restage relu(acc + bias) as bf16 into the same LDS tile
        // C/D frag layout: col = lane&15, row = (lane>>4)*4 + r  [m89-verified]
        #pragma unroll
        for (int nt = 0; nt < NT; ++nt) {
            const int col = wn * (COUT / 2) + nt * 16 + l15;
            const float bv = bias[col];
            #pragma unroll
            for (int mt = 0; mt < 2; ++mt) {
                const int lr0 = wm * 32 + mt * 16 + quad * 4;
                #pragma unroll
                for (int r = 0; r < 4; ++r)
                    As[lr0 + r][col] = f2bf(fmaxf(acc[mt][nt][r] + bv, 0.f));
            }
        }
        __syncthreads();

        // ---------- phase C: [64 x COUT] @ W3[C3 x COUT]^T, no bias/relu ----------
        constexpr int NT3 = C3 / 32;
        f32x4 acc3[2][NT3] = {};
        for (int k0 = 0; k0 < COUT; k0 += 32) {
            bf16x8 aF[2];
            #pragma unroll
            for (int mt = 0; mt < 2; ++mt)
                aF[mt] = *(const bf16x8*)&As[wm * 32 + mt * 16 + l15][k0 + quad * 8];
            bf16x8 bF[NT3];
            #pragma unroll
            for (int nt = 0; nt < NT3; ++nt) {
                const int col = wn * (C3 / 2) + nt * 16 + l15;
                bF[nt] = *(const bf16x8*)&W3[(size_t)col * COUT + k0 + quad * 8];
            }
            #pragma unroll
            for (int mt = 0; mt < 2; ++mt)
                #pragma unroll
                for (int nt = 0; nt < NT3; ++nt)
                    acc3[mt][nt] = __builtin_amdgcn_mfma_f32_16x16x32_bf16(
                        aF[mt], bF[nt], acc3[mt][nt], 0, 0, 0);
        }
        #pragma unroll
        for (int nt = 0; nt < NT3; ++nt) {
            const int col = wn * (C3 / 2) + nt * 16 + l15;
            #pragma unroll
            for (int mt = 0; mt < 2; ++mt) {
                const int row0 = rb + wm * 32 + mt * 16 + quad * 4;
                #pragma unroll
                for (int r = 0; r < 4; ++r) {
                    const int row = row0 + r;
                    if (row < N)
                        Y3[(size_t)row * C3 + col] = f2bf(acc3[mt][nt][r]);
                }
            }
        }
    }
}

extern "C" void kernel_launch(void* const* d_in, const int* in_sizes, int n_in,
                              void* d_out, int out_size, void* d_ws, size_t ws_size,
                              hipStream_t stream) {
    const float* x        = (const float*)d_in[0];
    const int*   edge_row = (const int*)d_in[1];
    const int*   edge_col = (const int*)d_in[2];
    const float* edge_val = (const float*)d_in[3];
    const float* W1       = (const float*)d_in[4];
    const float* b1       = (const float*)d_in[5];
    const float* W2       = (const float*)d_in[6];
    const float* b2       = (const float*)d_in[7];
    const float* W3       = (const float*)d_in[8];
    const float* b3       = (const float*)d_in[9];
    float* out = (float*)d_out;

    const int N = N_NODES, E = N_EDGES;
    const int NB = (N + SCAN_ELEMS - 1) / SCAN_ELEMS;   // 98

    // workspace layout (G2/H1 no longer materialize; xbf is reused for H3)
    short* xbf = (short*)d_ws;                    // [N,128] bf16 x; later H3
    short* Gbf = xbf + (size_t)N * IN_C;          // [N,256] bf16 G1
    short* W1b = Gbf + (size_t)N * HID_C;         // [256,128]
    short* W2b = W1b + HID_C * IN_C;              // [256,256]
    short* W3b = W2b + HID_C * HID_C;             // [128,256]
    int* deg = (int*)(((uintptr_t)(W3b + OUT_C * HID_C) + 15) & ~(uintptr_t)15);
    int* row_start = deg + N;                     // [N+1]
    int* rank      = row_start + (N + 1);         // [E]
    int* bsum      = rank + E;                    // [128]
    int2* epk      = (int2*)(((uintptr_t)(bsum + 128) + 15) & ~(uintptr_t)15);  // [E]

    // ---- build CSR (atomic-free scatter) + casts ----
    hipMemsetAsync(deg, 0, N * sizeof(int), stream);
    hist_rank<<<(E + 255) / 256, 256, 0, stream>>>(edge_row, deg, rank, E);
    scan1<<<NB, SCAN_BLOCK, 0, stream>>>(deg, row_start, bsum, N);
    scan3<<<(N + 256) / 256, 256, 0, stream>>>(row_start, bsum, NB, N, E);
    {
        int n0 = N * IN_C, n1 = HID_C * IN_C, n2 = HID_C * HID_C, n3 = OUT_C * HID_C;
        int total = E + (n0 + n1 + n2 + n3) / 4;   // both parts wave-aligned
        scatter_cast<<<(total + 255) / 256, 256, 0, stream>>>(
            edge_row, edge_col, edge_val, row_start, rank, epk, E,
            x, xbf, n0, W1, W1b, n1, W2, W2b, n2, W3, W3b, n3);
    }

    const int fgrid = (N + 63) / 64;   // 1563 blocks of 64 rows

    // Layer 1 fused: G1 = relu(spmm(x) @ W1.T + b1)
    spmm_gemm<IN_C, HID_C, false, 0><<<fgrid, 256, 0, stream>>>(
        xbf, row_start, epk, W1b, b1, nullptr, Gbf, nullptr, N);

    // Layers 2+3 fused: H3 = relu(spmm(G1) @ W2.T + b2) @ W3.T   (into xbf)
    spmm_gemm<HID_C, HID_C, true, OUT_C><<<fgrid, 256, 0, stream>>>(
        Gbf, row_start, epk, W2b, b2, W3b, nullptr, xbf, N);

    // Final: out = normalize(spmm(H3) + b3)
    spmm_gather<OUT_C, 2><<<(N + 3) / 4, 256, 0, stream>>>(
        xbf, row_start, epk, out, b3, N);
}